// Round 3
// baseline (146.175 us; speedup 1.0000x reference)
//
#include <hip/hip_runtime.h>

#define W0 0.4f
#define W1 1.6f
#define LN2F 0.69314718055994530942f

typedef float f32x4 __attribute__((ext_vector_type(4)));
typedef int   i32x4 __attribute__((ext_vector_type(4)));

// Round 3 probe: persistent-style software-pipelined streaming.
// 2048 blocks x 256 threads, 32 elems/thread as 4 iterations of
// (2 float4 + 2 int4), depth-2 register pipeline: issue iter k+1's loads,
// then compute iter k. Waves consume at vmcnt(4) and never fully drain --
// continuous request issue, matching the structure of the kernels that
// hit ~6.3 TB/s (m13 copy / fill at 6.5 TB/s), vs our one-shot bursts
// which all plateaued at 3.1 TB/s effective.

__global__ __launch_bounds__(256) void bce_reduce_kernel(
    const f32x4* __restrict__ in4,
    const i32x4* __restrict__ tg4,
    float* __restrict__ psum,
    unsigned int* __restrict__ pcnt)
{
    const int tid  = threadIdx.x;
    const int base = blockIdx.x * 2048 + tid;   // float4 units; block owns 8192 elems

    // Prologue: load iteration 0.
    f32x4 pa0 = in4[base];
    f32x4 pa1 = in4[base + 256];
    i32x4 ta0 = tg4[base];
    i32x4 ta1 = tg4[base + 256];

    float sumA = 0.0f, sumB = 0.0f;
    unsigned int corA = 0, corB = 0;

#define ELEM(P, T, S, C)                                              \
    {                                                                 \
        const bool pos = ((T) == 1);                                  \
        const float x  = pos ? (P) : (1.0f - (P));                    \
        const float wl = pos ? (W1 * LN2F) : (W0 * LN2F);             \
        S = __builtin_fmaf(__log2f(x), wl, S);                        \
        C += (((P) > 0.5f) == pos) ? 1u : 0u;                         \
    }
#define ELEM4(P, T)                                                   \
    ELEM(P.x, T.x, sumA, corA) ELEM(P.y, T.y, sumB, corB)             \
    ELEM(P.z, T.z, sumA, corA) ELEM(P.w, T.w, sumB, corB)

    // Steady state: 3 pipelined iterations + epilogue.
    #pragma unroll
    for (int i = 0; i < 3; ++i) {
        const int nb = base + (i + 1) * 512;
        f32x4 pb0 = in4[nb];
        f32x4 pb1 = in4[nb + 256];
        i32x4 tb0 = tg4[nb];
        i32x4 tb1 = tg4[nb + 256];
        // Fix issue order: next-iter loads go out before current compute.
        asm volatile("" : "+v"(pb0), "+v"(pb1), "+v"(tb0), "+v"(tb1));
        ELEM4(pa0, ta0) ELEM4(pa1, ta1)
        pa0 = pb0; pa1 = pb1; ta0 = tb0; ta1 = tb1;
    }
    ELEM4(pa0, ta0) ELEM4(pa1, ta1)
#undef ELEM4
#undef ELEM

    float sum = sumA + sumB;
    unsigned int correct = corA + corB;

    #pragma unroll
    for (int off = 32; off > 0; off >>= 1) {
        sum     += __shfl_down(sum, off, 64);
        correct += __shfl_down(correct, off, 64);
    }

    __shared__ float s_sum[4];
    __shared__ unsigned int s_cnt[4];
    const int lane = tid & 63;
    const int wave = tid >> 6;
    if (lane == 0) { s_sum[wave] = sum; s_cnt[wave] = correct; }
    __syncthreads();
    if (tid == 0) {
        psum[blockIdx.x] = s_sum[0] + s_sum[1] + s_sum[2] + s_sum[3];
        pcnt[blockIdx.x] = s_cnt[0] + s_cnt[1] + s_cnt[2] + s_cnt[3];
    }
}

__global__ __launch_bounds__(1024) void bce_finalize_kernel(
    const float* __restrict__ psum,
    const unsigned int* __restrict__ pcnt,
    float* __restrict__ out, int nblocks, int n)
{
    const int tid = threadIdx.x;
    double s = 0.0;
    unsigned long long c = 0;
    for (int k = tid; k < nblocks; k += 1024) {
        s += (double)psum[k];
        c += (unsigned long long)pcnt[k];
    }
    #pragma unroll
    for (int off = 32; off > 0; off >>= 1) {
        s += __shfl_down(s, off, 64);
        c += __shfl_down(c, off, 64);
    }
    __shared__ double sh_s[16];
    __shared__ unsigned long long sh_c[16];
    const int lane = tid & 63;
    const int wave = tid >> 6;
    if (lane == 0) { sh_s[wave] = s; sh_c[wave] = c; }
    __syncthreads();
    if (tid == 0) {
        double ts = 0.0;
        unsigned long long tc = 0;
        for (int w = 0; w < 16; ++w) { ts += sh_s[w]; tc += sh_c[w]; }
        double inv_n = 1.0 / (double)n;
        out[0] = (float)(-ts * inv_n);
        out[1] = (float)((double)tc * inv_n);
    }
}

extern "C" void kernel_launch(void* const* d_in, const int* in_sizes, int n_in,
                              void* d_out, int out_size, void* d_ws, size_t ws_size,
                              hipStream_t stream) {
    const f32x4* in4 = (const f32x4*)d_in[0];
    const i32x4* tg4 = (const i32x4*)d_in[1];
    float* out = (float*)d_out;
    int n = in_sizes[0];
    int nblocks = n >> 13;  // 8192 elems per block -> 2048 blocks

    float* psum = (float*)d_ws;
    unsigned int* pcnt = (unsigned int*)((char*)d_ws + (size_t)nblocks * sizeof(float));

    bce_reduce_kernel<<<nblocks, 256, 0, stream>>>(in4, tg4, psum, pcnt);
    bce_finalize_kernel<<<1, 1024, 0, stream>>>(psum, pcnt, out, nblocks, n);
}

// Round 4
// 136.875 us; speedup vs baseline: 1.0679x; 1.0679x over previous
//
#include <hip/hip_runtime.h>

#define W0 0.4f
#define W1 1.6f
#define LN2F 0.69314718055994530942f

typedef float f32x4 __attribute__((ext_vector_type(4)));
typedef int   i32x4 __attribute__((ext_vector_type(4)));

// Round 4 probe: NON-TEMPORAL loads.
// Theory: the harness's 268MB workspace poison sits dirty in the 256MiB
// Infinity Cache (beyond TCC, invisible to FETCH_SIZE/WRITE_SIZE). Our
// read-once stream allocates on L3 miss -> evicts a dirty line -> hidden
// 1:1 HBM writeback alongside every read. 134MB read + ~134MB writeback
// at 6.3 TB/s = 42.6us == the invariant time all 4 prior structures hit.
// nt loads skip cache allocation -> HBM traffic drops to compulsory 134MB.

__global__ __launch_bounds__(256) void bce_reduce_kernel(
    const f32x4* __restrict__ in4,
    const i32x4* __restrict__ tg4,
    float* __restrict__ psum,
    unsigned int* __restrict__ pcnt)
{
    const int base = blockIdx.x * 2048 + threadIdx.x;

    f32x4 p0 = __builtin_nontemporal_load(&in4[base]);
    i32x4 t0 = __builtin_nontemporal_load(&tg4[base]);
    f32x4 p1 = __builtin_nontemporal_load(&in4[base + 256]);
    i32x4 t1 = __builtin_nontemporal_load(&tg4[base + 256]);
    f32x4 p2 = __builtin_nontemporal_load(&in4[base + 512]);
    i32x4 t2 = __builtin_nontemporal_load(&tg4[base + 512]);
    f32x4 p3 = __builtin_nontemporal_load(&in4[base + 768]);
    i32x4 t3 = __builtin_nontemporal_load(&tg4[base + 768]);
    f32x4 p4 = __builtin_nontemporal_load(&in4[base + 1024]);
    i32x4 t4 = __builtin_nontemporal_load(&tg4[base + 1024]);
    f32x4 p5 = __builtin_nontemporal_load(&in4[base + 1280]);
    i32x4 t5 = __builtin_nontemporal_load(&tg4[base + 1280]);
    f32x4 p6 = __builtin_nontemporal_load(&in4[base + 1536]);
    i32x4 t6 = __builtin_nontemporal_load(&tg4[base + 1536]);
    f32x4 p7 = __builtin_nontemporal_load(&in4[base + 1792]);
    i32x4 t7 = __builtin_nontemporal_load(&tg4[base + 1792]);

    float sumA = 0.0f, sumB = 0.0f;
    unsigned int corA = 0, corB = 0;

#define ELEM(P, T, S, C)                                              \
    {                                                                 \
        const bool pos = ((T) == 1);                                  \
        const float x  = pos ? (P) : (1.0f - (P));                    \
        const float wl = pos ? (W1 * LN2F) : (W0 * LN2F);             \
        S = __builtin_fmaf(__log2f(x), wl, S);                        \
        C += (((P) > 0.5f) == pos) ? 1u : 0u;                         \
    }
#define ELEM4(P, T)                                                   \
    ELEM(P.x, T.x, sumA, corA) ELEM(P.y, T.y, sumB, corB)             \
    ELEM(P.z, T.z, sumA, corA) ELEM(P.w, T.w, sumB, corB)

    ELEM4(p0, t0) ELEM4(p1, t1) ELEM4(p2, t2) ELEM4(p3, t3)
    ELEM4(p4, t4) ELEM4(p5, t5) ELEM4(p6, t6) ELEM4(p7, t7)
#undef ELEM4
#undef ELEM

    float sum = sumA + sumB;
    unsigned int correct = corA + corB;

    #pragma unroll
    for (int off = 32; off > 0; off >>= 1) {
        sum     += __shfl_down(sum, off, 64);
        correct += __shfl_down(correct, off, 64);
    }

    __shared__ float s_sum[4];
    __shared__ unsigned int s_cnt[4];
    const int lane = threadIdx.x & 63;
    const int wave = threadIdx.x >> 6;
    if (lane == 0) { s_sum[wave] = sum; s_cnt[wave] = correct; }
    __syncthreads();
    if (threadIdx.x == 0) {
        psum[blockIdx.x] = s_sum[0] + s_sum[1] + s_sum[2] + s_sum[3];
        pcnt[blockIdx.x] = s_cnt[0] + s_cnt[1] + s_cnt[2] + s_cnt[3];
    }
}

__global__ __launch_bounds__(1024) void bce_finalize_kernel(
    const float* __restrict__ psum,
    const unsigned int* __restrict__ pcnt,
    float* __restrict__ out, int nblocks, int n)
{
    const int tid = threadIdx.x;
    double s = 0.0;
    unsigned long long c = 0;
    for (int k = tid; k < nblocks; k += 1024) {
        s += (double)psum[k];
        c += (unsigned long long)pcnt[k];
    }
    #pragma unroll
    for (int off = 32; off > 0; off >>= 1) {
        s += __shfl_down(s, off, 64);
        c += __shfl_down(c, off, 64);
    }
    __shared__ double sh_s[16];
    __shared__ unsigned long long sh_c[16];
    const int lane = tid & 63;
    const int wave = tid >> 6;
    if (lane == 0) { sh_s[wave] = s; sh_c[wave] = c; }
    __syncthreads();
    if (tid == 0) {
        double ts = 0.0;
        unsigned long long tc = 0;
        for (int w = 0; w < 16; ++w) { ts += sh_s[w]; tc += sh_c[w]; }
        double inv_n = 1.0 / (double)n;
        out[0] = (float)(-ts * inv_n);
        out[1] = (float)((double)tc * inv_n);
    }
}

extern "C" void kernel_launch(void* const* d_in, const int* in_sizes, int n_in,
                              void* d_out, int out_size, void* d_ws, size_t ws_size,
                              hipStream_t stream) {
    const f32x4* in4 = (const f32x4*)d_in[0];
    const i32x4* tg4 = (const i32x4*)d_in[1];
    float* out = (float*)d_out;
    int n = in_sizes[0];
    int nblocks = n >> 13;  // 8192 elems per block -> 2048 blocks

    float* psum = (float*)d_ws;
    unsigned int* pcnt = (unsigned int*)((char*)d_ws + (size_t)nblocks * sizeof(float));

    bce_reduce_kernel<<<nblocks, 256, 0, stream>>>(in4, tg4, psum, pcnt);
    bce_finalize_kernel<<<1, 1024, 0, stream>>>(psum, pcnt, out, nblocks, n);
}